// Round 6
// baseline (489.255 us; speedup 1.0000x reference)
//
#include <hip/hip_runtime.h>

typedef unsigned int uint32;
typedef unsigned short ushort16;

__device__ __forceinline__ ushort16 f2bf(float f) {
    union { float f; uint32 u; } v; v.f = f;
    uint32 r = v.u + 0x7fffu + ((v.u >> 16) & 1u);   // RNE
    return (ushort16)(r >> 16);
}
__device__ __forceinline__ float bflo(uint32 u) {            // low ushort -> f32
    union { uint32 u; float f; } v; v.u = u << 16; return v.f;
}
__device__ __forceinline__ float bfhi(uint32 u) {            // high ushort -> f32
    union { uint32 u; float f; } v; v.u = u & 0xffff0000u; return v.f;
}

#define BSH 6   // bucket = dst >> BSH  (64 nodes/bucket)

// ---------------- CSR build ----------------

__global__ void k_init(int* __restrict__ deg, int n) {
    int i = blockIdx.x * 256 + threadIdx.x;
    if (i < n) deg[i] = 0;
}

__global__ void k_count(const int* __restrict__ dst, int* __restrict__ deg, int e) {
    int i = blockIdx.x * 256 + threadIdx.x;
    if (i < e) atomicAdd(&deg[dst[i]], 1);
}

__global__ void k_inv(const int* __restrict__ deg, float* __restrict__ inv, int n) {
    int i = blockIdx.x * 256 + threadIdx.x;
    if (i < n) inv[i] = rsqrtf((float)deg[i] + 1.0f);
}

__global__ void k_scan1(const int* __restrict__ deg, int* __restrict__ rowstart,
                        int* __restrict__ blocksum, int n) {
    __shared__ int s[256];
    int tid = threadIdx.x;
    int gid = blockIdx.x * 256 + tid;
    int v = (gid < n) ? deg[gid] : 0;
    s[tid] = v;
    __syncthreads();
    for (int off = 1; off < 256; off <<= 1) {
        int t = (tid >= off) ? s[tid - off] : 0;
        __syncthreads();
        s[tid] += t;
        __syncthreads();
    }
    if (gid < n) rowstart[gid] = s[tid] - v;   // exclusive
    if (tid == 255) blocksum[blockIdx.x] = s[255];
}

__global__ void k_scan2(int* __restrict__ bs, int nb) {
    __shared__ int s[256];
    int tid = threadIdx.x;
    int v = (tid < nb) ? bs[tid] : 0;
    s[tid] = v;
    __syncthreads();
    for (int off = 1; off < 256; off <<= 1) {
        int t = (tid >= off) ? s[tid - off] : 0;
        __syncthreads();
        s[tid] += t;
        __syncthreads();
    }
    if (tid < nb) bs[tid] = s[tid] - v;
}

__global__ void k_scan3(int* __restrict__ rowstart, const int* __restrict__ boff,
                        int* __restrict__ cursor, int n, int e) {
    int i = blockIdx.x * 256 + threadIdx.x;
    if (i < n) {
        int r = rowstart[i] + boff[blockIdx.x];
        rowstart[i] = r;
        cursor[i] = r;
    }
    if (i == 0) rowstart[n] = e;
}

// bucket counts from deg: one wave per bucket (64 nodes = 64 lanes)
__global__ void k_bhist(const int* __restrict__ deg, int* __restrict__ bcnt,
                        int n, int nb) {
    int wave = threadIdx.x >> 6;
    int lane = threadIdx.x & 63;
    int b = blockIdx.x * 4 + wave;
    if (b >= nb) return;
    int node = (b << BSH) + lane;
    int v = (node < n) ? deg[node] : 0;
    #pragma unroll
    for (int off = 32; off > 0; off >>= 1) v += __shfl_down(v, off, 64);
    if (lane == 0) bcnt[b] = v;
}

// exclusive scan of bcnt[nb] (single block, chunked), init bcur
__global__ void k_bscan(const int* __restrict__ bcnt, int* __restrict__ bstart,
                        int* __restrict__ bcur, int nb, int e) {
    __shared__ int s[256];
    __shared__ int carry;
    int tid = threadIdx.x;
    if (tid == 0) carry = 0;
    __syncthreads();
    for (int base = 0; base < nb; base += 256) {
        int v = (base + tid < nb) ? bcnt[base + tid] : 0;
        s[tid] = v;
        __syncthreads();
        for (int off = 1; off < 256; off <<= 1) {
            int t = (tid >= off) ? s[tid - off] : 0;
            __syncthreads();
            s[tid] += t;
            __syncthreads();
        }
        int ex = s[tid] - v + carry;
        if (base + tid < nb) { bstart[base + tid] = ex; bcur[base + tid] = ex; }
        __syncthreads();
        if (tid == 0) carry += s[255];
        __syncthreads();
    }
    if (tid == 0) bstart[nb] = e;
}

// pass A: scatter {src,dst} records into dst-buckets (cache-local frontier)
__global__ void k_binA(const int* __restrict__ src, const int* __restrict__ dst,
                       int* __restrict__ bcur, int2* __restrict__ rec, int e) {
    int i = blockIdx.x * 256 + threadIdx.x;
    if (i < e) {
        int s = src[i];
        int d = dst[i];
        int p = atomicAdd(&bcur[d >> BSH], 1);
        rec[p] = make_int2(s, d);
    }
}

// pass B: one block per bucket; final scatter is bucket-local (L2-resident)
__global__ void k_fillB(const int2* __restrict__ rec, const int* __restrict__ bstart,
                        const float* __restrict__ inv, int* __restrict__ cursor,
                        int2* __restrict__ es, int nb) {
    int b = blockIdx.x;
    int st = bstart[b], en = bstart[b + 1];
    for (int i = st + threadIdx.x; i < en; i += 256) {
        int2 r = rec[i];
        int p = atomicAdd(&cursor[r.y], 1);
        es[p] = make_int2(r.x, __float_as_int(inv[r.x]));
    }
}

// ---------------- GEMM kernels (fp32 compute, bf16 output) ----------------

__global__ __launch_bounds__(256) void k_gemm1(const float* __restrict__ x,
                                               const float* __restrict__ W,
                                               ushort16* __restrict__ h, int n) {
    __shared__ float sW[128 * 128];   // 64 KiB
    __shared__ float sx[32 * 128];    // 16 KiB
    int tid = threadIdx.x;
    for (int i = tid * 4; i < 128 * 128; i += 1024)
        *(float4*)&sW[i] = *(const float4*)&W[i];
    int row0 = blockIdx.x * 32;
    for (int i = tid * 4; i < 32 * 128; i += 1024) {
        int r = row0 + (i >> 7);
        float4 v = (r < n) ? *(const float4*)&x[r * 128 + (i & 127)]
                           : make_float4(0.f, 0.f, 0.f, 0.f);
        *(float4*)&sx[i] = v;
    }
    __syncthreads();
    int c4 = (tid & 31) * 4;
    int rg = tid >> 5;
    float4 acc[4] = {};
    #pragma unroll 4
    for (int k = 0; k < 128; ++k) {
        float4 wv = *(const float4*)&sW[k * 128 + c4];
        #pragma unroll
        for (int i = 0; i < 4; ++i) {
            float xv = sx[(rg + 8 * i) * 128 + k];
            acc[i].x += xv * wv.x; acc[i].y += xv * wv.y;
            acc[i].z += xv * wv.z; acc[i].w += xv * wv.w;
        }
    }
    #pragma unroll
    for (int i = 0; i < 4; ++i) {
        int r = row0 + rg + 8 * i;
        if (r < n) {
            uint32 lo = (uint32)f2bf(acc[i].x) | ((uint32)f2bf(acc[i].y) << 16);
            uint32 hi = (uint32)f2bf(acc[i].z) | ((uint32)f2bf(acc[i].w) << 16);
            *(uint2*)&h[r * 128 + c4] = make_uint2(lo, hi);
        }
    }
}

__global__ __launch_bounds__(256) void k_gemm2(const float* __restrict__ a,
                                               const float* __restrict__ W,
                                               ushort16* __restrict__ h, int n) {
    __shared__ float sW[128 * 64];    // 32 KiB
    __shared__ float sx[64 * 128];    // 32 KiB
    int tid = threadIdx.x;
    for (int i = tid * 4; i < 128 * 64; i += 1024)
        *(float4*)&sW[i] = *(const float4*)&W[i];
    int row0 = blockIdx.x * 64;
    for (int i = tid * 4; i < 64 * 128; i += 1024) {
        int r = row0 + (i >> 7);
        float4 v = (r < n) ? *(const float4*)&a[r * 128 + (i & 127)]
                           : make_float4(0.f, 0.f, 0.f, 0.f);
        *(float4*)&sx[i] = v;
    }
    __syncthreads();
    int c4 = (tid & 15) * 4;
    int rg = tid >> 4;
    float4 acc[4] = {};
    #pragma unroll 4
    for (int k = 0; k < 128; ++k) {
        float4 wv = *(const float4*)&sW[k * 64 + c4];
        #pragma unroll
        for (int i = 0; i < 4; ++i) {
            float xv = sx[(rg + 16 * i) * 128 + k];
            acc[i].x += xv * wv.x; acc[i].y += xv * wv.y;
            acc[i].z += xv * wv.z; acc[i].w += xv * wv.w;
        }
    }
    #pragma unroll
    for (int i = 0; i < 4; ++i) {
        int r = row0 + rg + 16 * i;
        if (r < n) {
            uint32 lo = (uint32)f2bf(acc[i].x) | ((uint32)f2bf(acc[i].y) << 16);
            uint32 hi = (uint32)f2bf(acc[i].z) | ((uint32)f2bf(acc[i].w) << 16);
            *(uint2*)&h[r * 64 + c4] = make_uint2(lo, hi);
        }
    }
}

// ---------------- Gather (aggregation), bf16 source rows ----------------
// es[i] = {src, bits(inv_sqrt[src])}. One wave per destination node.
template <int COLS, bool RELU>
__global__ __launch_bounds__(256) void k_gather(const ushort16* __restrict__ h,
                                                const int* __restrict__ rowstart,
                                                const int2* __restrict__ es,
                                                const float* __restrict__ inv,
                                                const float* __restrict__ bias,
                                                float* __restrict__ out, int n) {
    int wave = threadIdx.x >> 6;
    int lane = threadIdx.x & 63;
    int node = blockIdx.x * 4 + wave;
    if (node >= n) return;
    int s0 = rowstart[node];
    int s1 = rowstart[node + 1];
    float iv = inv[node];

    if constexpr (COLS == 128) {
        int c = lane * 2;
        float accx = 0.f, accy = 0.f;
        int i = s0;
        for (; i + 8 <= s1; i += 8) {
            int   a[8];
            float w[8];
            uint32 u[8];
            #pragma unroll
            for (int j = 0; j < 8; ++j) {
                int2 r = es[i + j];
                a[j] = r.x;
                w[j] = __int_as_float(r.y);
            }
            #pragma unroll
            for (int j = 0; j < 8; ++j)
                u[j] = *(const uint32*)&h[(size_t)a[j] * 128 + c];
            #pragma unroll
            for (int j = 0; j < 8; ++j) {
                accx += w[j] * bflo(u[j]);
                accy += w[j] * bfhi(u[j]);
            }
        }
        for (; i < s1; ++i) {
            int2 r = es[i];
            uint32 u = *(const uint32*)&h[(size_t)r.x * 128 + c];
            float w = __int_as_float(r.y);
            accx += w * bflo(u);
            accy += w * bfhi(u);
        }
        uint32 us = *(const uint32*)&h[(size_t)node * 128 + c];
        float2 bb = *(const float2*)&bias[c];
        float ox = iv * accx + iv * iv * bflo(us) + bb.x;
        float oy = iv * accy + iv * iv * bfhi(us) + bb.y;
        if (RELU) { ox = fmaxf(ox, 0.f); oy = fmaxf(oy, 0.f); }
        *(float2*)&out[node * 128 + c] = make_float2(ox, oy);
    } else {
        int c = lane;
        float acc = 0.f;
        int i = s0;
        for (; i + 8 <= s1; i += 8) {
            int   a[8];
            float w[8];
            ushort16 u[8];
            #pragma unroll
            for (int j = 0; j < 8; ++j) {
                int2 r = es[i + j];
                a[j] = r.x;
                w[j] = __int_as_float(r.y);
            }
            #pragma unroll
            for (int j = 0; j < 8; ++j)
                u[j] = h[(size_t)a[j] * 64 + c];
            #pragma unroll
            for (int j = 0; j < 8; ++j)
                acc += w[j] * bflo((uint32)u[j]);
        }
        for (; i < s1; ++i) {
            int2 r = es[i];
            acc += __int_as_float(r.y) * bflo((uint32)h[(size_t)r.x * 64 + c]);
        }
        float self = bflo((uint32)h[(size_t)node * 64 + c]);
        float o = iv * acc + iv * iv * self + bias[c];
        if (RELU) o = fmaxf(o, 0.f);
        out[node * 64 + c] = o;
    }
}

// ---------------- launcher ----------------

extern "C" void kernel_launch(void* const* d_in, const int* in_sizes, int n_in,
                              void* d_out, int out_size, void* d_ws, size_t ws_size,
                              hipStream_t stream) {
    const float* x  = (const float*)d_in[0];
    const int*   ei = (const int*)d_in[1];
    const float* W1 = (const float*)d_in[2];
    const float* b1 = (const float*)d_in[3];
    const float* W2 = (const float*)d_in[4];
    const float* b2 = (const float*)d_in[5];
    float* out = (float*)d_out;

    const int N = in_sizes[0] / 128;   // 50000
    const int E = in_sizes[1] / 2;     // 800000
    const int NB = (N + 63) >> BSH;    // 782 buckets
    const int* src = ei;
    const int* dstp = ei + E;

    char* p = (char*)d_ws;
    auto take = [&](size_t bytes) {
        char* r = p;
        p += (bytes + 255) & ~(size_t)255;
        return r;
    };
    int*      deg      = (int*)take((size_t)N * 4);
    float*    inv      = (float*)take((size_t)N * 4);
    int*      rowstart = (int*)take((size_t)(N + 1) * 4);
    int*      cursor   = (int*)take((size_t)N * 4);
    int*      blocksum = (int*)take(256 * 4);
    int*      bcnt     = (int*)take((size_t)NB * 4);
    int*      bstart   = (int*)take((size_t)(NB + 1) * 4);
    int*      bcur     = (int*)take((size_t)NB * 4);
    int2*     rec      = (int2*)take((size_t)E * 8);
    int2*     es       = (int2*)take((size_t)E * 8);
    ushort16* h1       = (ushort16*)take((size_t)N * 128 * 2);  // bf16
    float*    act1     = (float*)take((size_t)N * 128 * 4);     // fp32
    ushort16* h2       = (ushort16*)h1;  // h1 dead after gather-1

    const int nbN = (N + 255) / 256;
    const int nbE = (E + 255) / 256;

    k_init <<<nbN, 256, 0, stream>>>(deg, N);
    k_count<<<nbE, 256, 0, stream>>>(dstp, deg, E);
    k_inv  <<<nbN, 256, 0, stream>>>(deg, inv, N);
    k_scan1<<<nbN, 256, 0, stream>>>(deg, rowstart, blocksum, N);
    k_scan2<<<1, 256, 0, stream>>>(blocksum, nbN);
    k_scan3<<<nbN, 256, 0, stream>>>(rowstart, blocksum, cursor, N, E);
    k_bhist<<<(NB + 3) / 4, 256, 0, stream>>>(deg, bcnt, N, NB);
    k_bscan<<<1, 256, 0, stream>>>(bcnt, bstart, bcur, NB, E);
    k_binA <<<nbE, 256, 0, stream>>>(src, dstp, bcur, rec, E);
    k_fillB<<<NB, 256, 0, stream>>>(rec, bstart, inv, cursor, es, NB);

    k_gemm1<<<(N + 31) / 32, 256, 0, stream>>>(x, W1, h1, N);
    k_gather<128, true><<<(N + 3) / 4, 256, 0, stream>>>(h1, rowstart, es, inv, b1, act1, N);
    k_gemm2<<<(N + 63) / 64, 256, 0, stream>>>(act1, W2, h2, N);
    k_gather<64, false><<<(N + 3) / 4, 256, 0, stream>>>(h2, rowstart, es, inv, b2, out, N);
}

// Round 7
// 259.490 us; speedup vs baseline: 1.8854x; 1.8854x over previous
//
#include <hip/hip_runtime.h>

typedef unsigned int uint32;
typedef unsigned short ushort16;

__device__ __forceinline__ ushort16 f2bf(float f) {
    union { float f; uint32 u; } v; v.f = f;
    uint32 r = v.u + 0x7fffu + ((v.u >> 16) & 1u);   // RNE
    return (ushort16)(r >> 16);
}
__device__ __forceinline__ float bflo(uint32 u) {            // low ushort -> f32
    union { uint32 u; float f; } v; v.u = u << 16; return v.f;
}
__device__ __forceinline__ float bfhi(uint32 u) {            // high ushort -> f32
    union { uint32 u; float f; } v; v.u = u & 0xffff0000u; return v.f;
}

#define BSH 6       // bucket = dst >> 6 (64 nodes/bucket)
#define NBMAX 1024  // max buckets (N=50000 -> 782)
#define CHUNK 4096  // edges per block in binning kernels

// ---------------- binned CSR build (contention-free) ----------------

__global__ void k_zerob(int* __restrict__ b, int nb) {
    int i = blockIdx.x * 256 + threadIdx.x;
    if (i < nb) b[i] = 0;
}

// bucket histogram, LDS-aggregated: ~196 global atomics per bucket total
__global__ __launch_bounds__(256) void k_bcount(const int* __restrict__ dst,
                                                int* __restrict__ bcnt, int e, int nb) {
    __shared__ int cnt[NBMAX];
    for (int i = threadIdx.x; i < nb; i += 256) cnt[i] = 0;
    __syncthreads();
    int base = blockIdx.x * CHUNK;
    int end = min(e, base + CHUNK);
    for (int i = base + threadIdx.x; i < end; i += 256)
        atomicAdd(&cnt[dst[i] >> BSH], 1);
    __syncthreads();
    for (int i = threadIdx.x; i < nb; i += 256) {
        int c = cnt[i];
        if (c) atomicAdd(&bcnt[i], c);
    }
}

// exclusive scan of bcnt[nb] (single block, chunked), init bcur
__global__ void k_bscan(const int* __restrict__ bcnt, int* __restrict__ bstart,
                        int* __restrict__ bcur, int nb, int e) {
    __shared__ int s[256];
    __shared__ int carry;
    int tid = threadIdx.x;
    if (tid == 0) carry = 0;
    __syncthreads();
    for (int base = 0; base < nb; base += 256) {
        int v = (base + tid < nb) ? bcnt[base + tid] : 0;
        s[tid] = v;
        __syncthreads();
        for (int off = 1; off < 256; off <<= 1) {
            int t = (tid >= off) ? s[tid - off] : 0;
            __syncthreads();
            s[tid] += t;
            __syncthreads();
        }
        int ex = s[tid] - v + carry;
        if (base + tid < nb) { bstart[base + tid] = ex; bcur[base + tid] = ex; }
        __syncthreads();
        if (tid == 0) carry += s[255];
        __syncthreads();
    }
    if (tid == 0) bstart[nb] = e;
}

// pass A: LDS-aggregated chunk reservation + scatter {src,dst} to bucket runs.
// Per-block contiguous runs per bucket -> line-filling writes; global atomics
// reduced 800K -> ~150K spread over 782 addresses.
__global__ __launch_bounds__(256) void k_binA2(const int* __restrict__ src,
                                               const int* __restrict__ dst,
                                               int* __restrict__ bcur,
                                               int2* __restrict__ rec, int e, int nb) {
    __shared__ int cnt[NBMAX];
    __shared__ int bas[NBMAX];
    __shared__ int off[NBMAX];
    for (int i = threadIdx.x; i < nb; i += 256) { cnt[i] = 0; off[i] = 0; }
    __syncthreads();
    int base = blockIdx.x * CHUNK;
    int end = min(e, base + CHUNK);
    for (int i = base + threadIdx.x; i < end; i += 256)
        atomicAdd(&cnt[dst[i] >> BSH], 1);
    __syncthreads();
    for (int i = threadIdx.x; i < nb; i += 256) {
        int c = cnt[i];
        if (c) bas[i] = atomicAdd(&bcur[i], c);
    }
    __syncthreads();
    for (int i = base + threadIdx.x; i < end; i += 256) {
        int s = src[i];
        int d = dst[i];
        int b = d >> BSH;
        int p = bas[b] + atomicAdd(&off[b], 1);
        rec[p] = make_int2(s, d);
    }
}

// per-bucket degree + rowstart + inv from binned records (no global atomics).
// Replaces k_count + scan1/2/3 entirely.
__global__ __launch_bounds__(256) void k_degB(const int2* __restrict__ rec,
                                              const int* __restrict__ bstart,
                                              int* __restrict__ rowstart,
                                              float* __restrict__ inv, int n, int e) {
    __shared__ int cnt[64];
    int b = blockIdx.x;
    int st = bstart[b], en = bstart[b + 1];
    if (threadIdx.x < 64) cnt[threadIdx.x] = 0;
    __syncthreads();
    for (int i = st + threadIdx.x; i < en; i += 256)
        atomicAdd(&cnt[rec[i].y & 63], 1);
    __syncthreads();
    if (threadIdx.x < 64) {
        int c = cnt[threadIdx.x];
        int incl = c;
        #pragma unroll
        for (int o2 = 1; o2 < 64; o2 <<= 1) {
            int t = __shfl_up(incl, o2, 64);
            if ((int)threadIdx.x >= o2) incl += t;
        }
        int node = (b << BSH) + threadIdx.x;
        if (node < n) {
            rowstart[node] = st + incl - c;           // exclusive within bucket
            inv[node] = rsqrtf((float)c + 1.0f);
        }
    }
    if (b == 0 && threadIdx.x == 0) rowstart[n] = e;
}

// pass B: scatter to final CSR positions. Cursors in LDS (zero global atomic
// contention); writes confined to this bucket's private ~8KB window (L2-local,
// lines fully filled before eviction).
__global__ __launch_bounds__(256) void k_fillB2(const int2* __restrict__ rec,
                                                const int* __restrict__ bstart,
                                                const int* __restrict__ rowstart,
                                                const float* __restrict__ inv,
                                                int2* __restrict__ es, int n) {
    __shared__ int cur[64];
    int b = blockIdx.x;
    int st = bstart[b], en = bstart[b + 1];
    if (threadIdx.x < 64) {
        int node = (b << BSH) + threadIdx.x;
        cur[threadIdx.x] = (node < n) ? (rowstart[node] - st) : 0;
    }
    __syncthreads();
    for (int i = st + threadIdx.x; i < en; i += 256) {
        int2 r = rec[i];
        int slot = atomicAdd(&cur[r.y & 63], 1);
        es[st + slot] = make_int2(r.x, __float_as_int(inv[r.x]));
    }
}

// ---------------- GEMM kernels (fp32 compute, bf16 output) ----------------

__global__ __launch_bounds__(256) void k_gemm1(const float* __restrict__ x,
                                               const float* __restrict__ W,
                                               ushort16* __restrict__ h, int n) {
    __shared__ float sW[128 * 128];   // 64 KiB
    __shared__ float sx[32 * 128];    // 16 KiB
    int tid = threadIdx.x;
    for (int i = tid * 4; i < 128 * 128; i += 1024)
        *(float4*)&sW[i] = *(const float4*)&W[i];
    int row0 = blockIdx.x * 32;
    for (int i = tid * 4; i < 32 * 128; i += 1024) {
        int r = row0 + (i >> 7);
        float4 v = (r < n) ? *(const float4*)&x[r * 128 + (i & 127)]
                           : make_float4(0.f, 0.f, 0.f, 0.f);
        *(float4*)&sx[i] = v;
    }
    __syncthreads();
    int c4 = (tid & 31) * 4;
    int rg = tid >> 5;
    float4 acc[4] = {};
    #pragma unroll 4
    for (int k = 0; k < 128; ++k) {
        float4 wv = *(const float4*)&sW[k * 128 + c4];
        #pragma unroll
        for (int i = 0; i < 4; ++i) {
            float xv = sx[(rg + 8 * i) * 128 + k];
            acc[i].x += xv * wv.x; acc[i].y += xv * wv.y;
            acc[i].z += xv * wv.z; acc[i].w += xv * wv.w;
        }
    }
    #pragma unroll
    for (int i = 0; i < 4; ++i) {
        int r = row0 + rg + 8 * i;
        if (r < n) {
            uint32 lo = (uint32)f2bf(acc[i].x) | ((uint32)f2bf(acc[i].y) << 16);
            uint32 hi = (uint32)f2bf(acc[i].z) | ((uint32)f2bf(acc[i].w) << 16);
            *(uint2*)&h[r * 128 + c4] = make_uint2(lo, hi);
        }
    }
}

__global__ __launch_bounds__(256) void k_gemm2(const float* __restrict__ a,
                                               const float* __restrict__ W,
                                               ushort16* __restrict__ h, int n) {
    __shared__ float sW[128 * 64];    // 32 KiB
    __shared__ float sx[64 * 128];    // 32 KiB
    int tid = threadIdx.x;
    for (int i = tid * 4; i < 128 * 64; i += 1024)
        *(float4*)&sW[i] = *(const float4*)&W[i];
    int row0 = blockIdx.x * 64;
    for (int i = tid * 4; i < 64 * 128; i += 1024) {
        int r = row0 + (i >> 7);
        float4 v = (r < n) ? *(const float4*)&a[r * 128 + (i & 127)]
                           : make_float4(0.f, 0.f, 0.f, 0.f);
        *(float4*)&sx[i] = v;
    }
    __syncthreads();
    int c4 = (tid & 15) * 4;
    int rg = tid >> 4;
    float4 acc[4] = {};
    #pragma unroll 4
    for (int k = 0; k < 128; ++k) {
        float4 wv = *(const float4*)&sW[k * 64 + c4];
        #pragma unroll
        for (int i = 0; i < 4; ++i) {
            float xv = sx[(rg + 16 * i) * 128 + k];
            acc[i].x += xv * wv.x; acc[i].y += xv * wv.y;
            acc[i].z += xv * wv.z; acc[i].w += xv * wv.w;
        }
    }
    #pragma unroll
    for (int i = 0; i < 4; ++i) {
        int r = row0 + rg + 16 * i;
        if (r < n) {
            uint32 lo = (uint32)f2bf(acc[i].x) | ((uint32)f2bf(acc[i].y) << 16);
            uint32 hi = (uint32)f2bf(acc[i].z) | ((uint32)f2bf(acc[i].w) << 16);
            *(uint2*)&h[r * 64 + c4] = make_uint2(lo, hi);
        }
    }
}

// ---------------- Gather (aggregation), bf16 source rows ----------------
// es[i] = {src, bits(inv_sqrt[src])}. One wave per destination node.
template <int COLS, bool RELU>
__global__ __launch_bounds__(256) void k_gather(const ushort16* __restrict__ h,
                                                const int* __restrict__ rowstart,
                                                const int2* __restrict__ es,
                                                const float* __restrict__ inv,
                                                const float* __restrict__ bias,
                                                float* __restrict__ out, int n) {
    int wave = threadIdx.x >> 6;
    int lane = threadIdx.x & 63;
    int node = blockIdx.x * 4 + wave;
    if (node >= n) return;
    int s0 = rowstart[node];
    int s1 = rowstart[node + 1];
    float iv = inv[node];

    if constexpr (COLS == 128) {
        int c = lane * 2;
        float accx = 0.f, accy = 0.f;
        int i = s0;
        for (; i + 8 <= s1; i += 8) {
            int   a[8];
            float w[8];
            uint32 u[8];
            #pragma unroll
            for (int j = 0; j < 8; ++j) {
                int2 r = es[i + j];
                a[j] = r.x;
                w[j] = __int_as_float(r.y);
            }
            #pragma unroll
            for (int j = 0; j < 8; ++j)
                u[j] = *(const uint32*)&h[(size_t)a[j] * 128 + c];
            #pragma unroll
            for (int j = 0; j < 8; ++j) {
                accx += w[j] * bflo(u[j]);
                accy += w[j] * bfhi(u[j]);
            }
        }
        for (; i < s1; ++i) {
            int2 r = es[i];
            uint32 u = *(const uint32*)&h[(size_t)r.x * 128 + c];
            float w = __int_as_float(r.y);
            accx += w * bflo(u);
            accy += w * bfhi(u);
        }
        uint32 us = *(const uint32*)&h[(size_t)node * 128 + c];
        float2 bb = *(const float2*)&bias[c];
        float ox = iv * accx + iv * iv * bflo(us) + bb.x;
        float oy = iv * accy + iv * iv * bfhi(us) + bb.y;
        if (RELU) { ox = fmaxf(ox, 0.f); oy = fmaxf(oy, 0.f); }
        *(float2*)&out[node * 128 + c] = make_float2(ox, oy);
    } else {
        int c = lane;
        float acc = 0.f;
        int i = s0;
        for (; i + 8 <= s1; i += 8) {
            int   a[8];
            float w[8];
            ushort16 u[8];
            #pragma unroll
            for (int j = 0; j < 8; ++j) {
                int2 r = es[i + j];
                a[j] = r.x;
                w[j] = __int_as_float(r.y);
            }
            #pragma unroll
            for (int j = 0; j < 8; ++j)
                u[j] = h[(size_t)a[j] * 64 + c];
            #pragma unroll
            for (int j = 0; j < 8; ++j)
                acc += w[j] * bflo((uint32)u[j]);
        }
        for (; i < s1; ++i) {
            int2 r = es[i];
            acc += __int_as_float(r.y) * bflo((uint32)h[(size_t)r.x * 64 + c]);
        }
        float self = bflo((uint32)h[(size_t)node * 64 + c]);
        float o = iv * acc + iv * iv * self + bias[c];
        if (RELU) o = fmaxf(o, 0.f);
        out[node * 64 + c] = o;
    }
}

// ---------------- launcher ----------------

extern "C" void kernel_launch(void* const* d_in, const int* in_sizes, int n_in,
                              void* d_out, int out_size, void* d_ws, size_t ws_size,
                              hipStream_t stream) {
    const float* x  = (const float*)d_in[0];
    const int*   ei = (const int*)d_in[1];
    const float* W1 = (const float*)d_in[2];
    const float* b1 = (const float*)d_in[3];
    const float* W2 = (const float*)d_in[4];
    const float* b2 = (const float*)d_in[5];
    float* out = (float*)d_out;

    const int N = in_sizes[0] / 128;   // 50000
    const int E = in_sizes[1] / 2;     // 800000
    const int NB = (N + 63) >> BSH;    // 782 buckets
    const int* src = ei;
    const int* dstp = ei + E;

    char* p = (char*)d_ws;
    auto take = [&](size_t bytes) {
        char* r = p;
        p += (bytes + 255) & ~(size_t)255;
        return r;
    };
    float*    inv      = (float*)take((size_t)N * 4);
    int*      rowstart = (int*)take((size_t)(N + 1) * 4);
    int*      bcnt     = (int*)take((size_t)NB * 4);
    int*      bstart   = (int*)take((size_t)(NB + 1) * 4);
    int*      bcur     = (int*)take((size_t)NB * 4);
    int2*     rec      = (int2*)take((size_t)E * 8);
    int2*     es       = (int2*)take((size_t)E * 8);
    ushort16* h1       = (ushort16*)take((size_t)N * 128 * 2);  // bf16
    float*    act1     = (float*)take((size_t)N * 128 * 4);     // fp32
    ushort16* h2       = (ushort16*)h1;  // h1 dead after gather-1

    const int nbC = (E + CHUNK - 1) / CHUNK;   // 196 chunk-blocks

    k_zerob <<<(NB + 255) / 256, 256, 0, stream>>>(bcnt, NB);
    k_bcount<<<nbC, 256, 0, stream>>>(dstp, bcnt, E, NB);
    k_bscan <<<1, 256, 0, stream>>>(bcnt, bstart, bcur, NB, E);
    k_binA2 <<<nbC, 256, 0, stream>>>(src, dstp, bcur, rec, E, NB);
    k_degB  <<<NB, 256, 0, stream>>>(rec, bstart, rowstart, inv, N, E);
    k_fillB2<<<NB, 256, 0, stream>>>(rec, bstart, rowstart, inv, es, N);

    k_gemm1<<<(N + 31) / 32, 256, 0, stream>>>(x, W1, h1, N);
    k_gather<128, true><<<(N + 3) / 4, 256, 0, stream>>>(h1, rowstart, es, inv, b1, act1, N);
    k_gemm2<<<(N + 63) / 64, 256, 0, stream>>>(act1, W2, h2, N);
    k_gather<64, false><<<(N + 3) / 4, 256, 0, stream>>>(h2, rowstart, es, inv, b2, out, N);
}

// Round 8
// 240.062 us; speedup vs baseline: 2.0380x; 1.0809x over previous
//
#include <hip/hip_runtime.h>

typedef unsigned int uint32;
typedef unsigned short ush;
typedef __attribute__((ext_vector_type(8))) short short8;   // bf16x8 MFMA frag
typedef __attribute__((ext_vector_type(4))) float f32x4;    // fp32x4 acc frag

__device__ __forceinline__ ush f2bf(float f) {
    union { float f; uint32 u; } v; v.f = f;
    uint32 r = v.u + 0x7fffu + ((v.u >> 16) & 1u);   // RNE
    return (ush)(r >> 16);
}
__device__ __forceinline__ float bfl(uint32 u) {             // low ushort -> f32
    union { uint32 u; float f; } v; v.u = u << 16; return v.f;
}
__device__ __forceinline__ float bfh(uint32 u) {             // high ushort -> f32
    union { uint32 u; float f; } v; v.u = u & 0xffff0000u; return v.f;
}

#define BSH 6       // bucket = dst >> 6 (64 nodes/bucket)
#define NBMAX 1024  // max buckets (N=50000 -> 782)
#define CHUNK 4096  // edges per block in binning kernels

// ---------------- binned CSR build (contention-free) ----------------

__global__ void k_zerob(int* __restrict__ b, int nb) {
    int i = blockIdx.x * 256 + threadIdx.x;
    if (i < nb) b[i] = 0;
}

__global__ __launch_bounds__(256) void k_bcount(const int* __restrict__ dst,
                                                int* __restrict__ bcnt, int e, int nb) {
    __shared__ int cnt[NBMAX];
    for (int i = threadIdx.x; i < nb; i += 256) cnt[i] = 0;
    __syncthreads();
    int base = blockIdx.x * CHUNK;
    int end = min(e, base + CHUNK);
    for (int i = base + threadIdx.x; i < end; i += 256)
        atomicAdd(&cnt[dst[i] >> BSH], 1);
    __syncthreads();
    for (int i = threadIdx.x; i < nb; i += 256) {
        int c = cnt[i];
        if (c) atomicAdd(&bcnt[i], c);
    }
}

__global__ void k_bscan(const int* __restrict__ bcnt, int* __restrict__ bstart,
                        int* __restrict__ bcur, int nb, int e) {
    __shared__ int s[256];
    __shared__ int carry;
    int tid = threadIdx.x;
    if (tid == 0) carry = 0;
    __syncthreads();
    for (int base = 0; base < nb; base += 256) {
        int v = (base + tid < nb) ? bcnt[base + tid] : 0;
        s[tid] = v;
        __syncthreads();
        for (int off = 1; off < 256; off <<= 1) {
            int t = (tid >= off) ? s[tid - off] : 0;
            __syncthreads();
            s[tid] += t;
            __syncthreads();
        }
        int ex = s[tid] - v + carry;
        if (base + tid < nb) { bstart[base + tid] = ex; bcur[base + tid] = ex; }
        __syncthreads();
        if (tid == 0) carry += s[255];
        __syncthreads();
    }
    if (tid == 0) bstart[nb] = e;
}

__global__ __launch_bounds__(256) void k_binA2(const int* __restrict__ src,
                                               const int* __restrict__ dst,
                                               int* __restrict__ bcur,
                                               int2* __restrict__ rec, int e, int nb) {
    __shared__ int cnt[NBMAX];
    __shared__ int bas[NBMAX];
    __shared__ int off[NBMAX];
    for (int i = threadIdx.x; i < nb; i += 256) { cnt[i] = 0; off[i] = 0; }
    __syncthreads();
    int base = blockIdx.x * CHUNK;
    int end = min(e, base + CHUNK);
    for (int i = base + threadIdx.x; i < end; i += 256)
        atomicAdd(&cnt[dst[i] >> BSH], 1);
    __syncthreads();
    for (int i = threadIdx.x; i < nb; i += 256) {
        int c = cnt[i];
        if (c) bas[i] = atomicAdd(&bcur[i], c);
    }
    __syncthreads();
    for (int i = base + threadIdx.x; i < end; i += 256) {
        int s = src[i];
        int d = dst[i];
        int b = d >> BSH;
        int p = bas[b] + atomicAdd(&off[b], 1);
        rec[p] = make_int2(s, d);
    }
}

__global__ __launch_bounds__(256) void k_degB(const int2* __restrict__ rec,
                                              const int* __restrict__ bstart,
                                              int* __restrict__ rowstart,
                                              float* __restrict__ inv, int n, int e) {
    __shared__ int cnt[64];
    int b = blockIdx.x;
    int st = bstart[b], en = bstart[b + 1];
    if (threadIdx.x < 64) cnt[threadIdx.x] = 0;
    __syncthreads();
    for (int i = st + threadIdx.x; i < en; i += 256)
        atomicAdd(&cnt[rec[i].y & 63], 1);
    __syncthreads();
    if (threadIdx.x < 64) {
        int c = cnt[threadIdx.x];
        int incl = c;
        #pragma unroll
        for (int o2 = 1; o2 < 64; o2 <<= 1) {
            int t = __shfl_up(incl, o2, 64);
            if ((int)threadIdx.x >= o2) incl += t;
        }
        int node = (b << BSH) + threadIdx.x;
        if (node < n) {
            rowstart[node] = st + incl - c;
            inv[node] = rsqrtf((float)c + 1.0f);
        }
    }
    if (b == 0 && threadIdx.x == 0) rowstart[n] = e;
}

__global__ __launch_bounds__(256) void k_fillB2(const int2* __restrict__ rec,
                                                const int* __restrict__ bstart,
                                                const int* __restrict__ rowstart,
                                                const float* __restrict__ inv,
                                                int2* __restrict__ es, int n) {
    __shared__ int cur[64];
    int b = blockIdx.x;
    int st = bstart[b], en = bstart[b + 1];
    if (threadIdx.x < 64) {
        int node = (b << BSH) + threadIdx.x;
        cur[threadIdx.x] = (node < n) ? (rowstart[node] - st) : 0;
    }
    __syncthreads();
    for (int i = st + threadIdx.x; i < en; i += 256) {
        int2 r = rec[i];
        int slot = atomicAdd(&cur[r.y & 63], 1);
        es[st + slot] = make_int2(r.x, __float_as_int(inv[r.x]));
    }
}

// ---------------- W pre-conversion: fp32 [K][cout] -> bf16 hi/lo, transposed
// [col][K] with 16B XOR swizzle pre-applied (ready for linear LDS staging).
__global__ void k_wcvt(const float* __restrict__ W, ush* __restrict__ wh,
                       ush* __restrict__ wl, int csh, int total) {
    int i = blockIdx.x * 256 + threadIdx.x;
    if (i >= total) return;
    int k = i >> csh;
    int col = i & ((1 << csh) - 1);
    float w = W[i];
    ush hi = f2bf(w);
    ush lo = f2bf(w - bfl((uint32)hi));
    int byte = ((col * 128 + k) * 2) ^ ((col & 7) << 4);
    *(ush*)((char*)wh + byte) = hi;
    *(ush*)((char*)wl + byte) = lo;
}

// ---------------- MFMA GEMM: h[n,COUT](bf16) = x[n,128](fp32) @ W ----------
// bf16x3 split precision. Block: 128 rows x COUT cols, 4 waves (2x2),
// wave tile: 64 rows x COUT/2 cols. K=128 one-shot (no K tiling).
// Layouts (verified m89): A: row=lane&15, k=(lane>>4)*8+j ; B: col=lane&15,
// same k ; C: col=lane&15, row=(lane>>4)*4+reg.
template <int COUT>
__global__ __launch_bounds__(256) void k_gemm_mfma(const float* __restrict__ x,
                                                   const ush* __restrict__ gwh,
                                                   const ush* __restrict__ gwl,
                                                   ush* __restrict__ h, int n) {
    constexpr int CT = COUT / 32;          // col-tiles per wave (4 or 2)
    __shared__ short xh[128 * 128];        // 32 KiB
    __shared__ short xl[128 * 128];        // 32 KiB
    __shared__ short wh[COUT * 128];       // 32 or 16 KiB
    __shared__ short wl[COUT * 128];
    int tid = threadIdx.x;
    int row0 = blockIdx.x * 128;

    // stage W (already transposed+swizzled bf16): linear copy
    for (int i = tid; i < COUT * 16; i += 256) {   // COUT*128/8 short8 units
        ((short8*)wh)[i] = ((const short8*)gwh)[i];
        ((short8*)wl)[i] = ((const short8*)gwl)[i];
    }
    // stage x: fp32 -> hi/lo bf16, swizzled
    #pragma unroll
    for (int i = 0; i < 8; ++i) {
        int rl = (tid >> 4) + i * 16;
        int k0 = (tid & 15) * 8;
        int row = row0 + rl;
        float f[8];
        if (row < n) {
            float4 p0 = *(const float4*)&x[(size_t)row * 128 + k0];
            float4 p1 = *(const float4*)&x[(size_t)row * 128 + k0 + 4];
            f[0] = p0.x; f[1] = p0.y; f[2] = p0.z; f[3] = p0.w;
            f[4] = p1.x; f[5] = p1.y; f[6] = p1.z; f[7] = p1.w;
        } else {
            #pragma unroll
            for (int j = 0; j < 8; ++j) f[j] = 0.f;
        }
        short8 hi, lo;
        #pragma unroll
        for (int j = 0; j < 8; ++j) {
            ush hb = f2bf(f[j]);
            hi[j] = (short)hb;
            lo[j] = (short)f2bf(f[j] - bfl((uint32)hb));
        }
        int byte = (rl * 256 + k0 * 2) ^ ((rl & 7) << 4);
        *(short8*)((char*)xh + byte) = hi;
        *(short8*)((char*)xl + byte) = lo;
    }
    __syncthreads();

    int wid = tid >> 6, lane = tid & 63;
    int wr = wid >> 1, wc = wid & 1;
    int arow = wr * 64;                    // local row base of wave
    int bcol = wc * (COUT / 2);            // col base of wave
    int l15 = lane & 15, kg = lane >> 4;

    f32x4 acc[4][CT];
    #pragma unroll
    for (int rt = 0; rt < 4; ++rt)
        #pragma unroll
        for (int ct = 0; ct < CT; ++ct)
            acc[rt][ct] = (f32x4){0.f, 0.f, 0.f, 0.f};

    #pragma unroll
    for (int ks = 0; ks < 4; ++ks) {
        short8 ah[4], al[4];
        #pragma unroll
        for (int rt = 0; rt < 4; ++rt) {
            int r = arow + rt * 16 + l15;
            int byte = (r * 256 + ks * 64 + kg * 16) ^ ((r & 7) << 4);
            ah[rt] = *(const short8*)((const char*)xh + byte);
            al[rt] = *(const short8*)((const char*)xl + byte);
        }
        #pragma unroll
        for (int ct = 0; ct < CT; ++ct) {
            int c = bcol + ct * 16 + l15;
            int byte = (c * 256 + ks * 64 + kg * 16) ^ ((c & 7) << 4);
            short8 bh = *(const short8*)((const char*)wh + byte);
            short8 bl = *(const short8*)((const char*)wl + byte);
            #pragma unroll
            for (int rt = 0; rt < 4; ++rt) {
                acc[rt][ct] = __builtin_amdgcn_mfma_f32_16x16x32_bf16(ah[rt], bh, acc[rt][ct], 0, 0, 0);
                acc[rt][ct] = __builtin_amdgcn_mfma_f32_16x16x32_bf16(al[rt], bh, acc[rt][ct], 0, 0, 0);
                acc[rt][ct] = __builtin_amdgcn_mfma_f32_16x16x32_bf16(ah[rt], bl, acc[rt][ct], 0, 0, 0);
            }
        }
    }

    int rq = kg * 4;
    #pragma unroll
    for (int rt = 0; rt < 4; ++rt) {
        #pragma unroll
        for (int ct = 0; ct < CT; ++ct) {
            int col = bcol + ct * 16 + l15;
            #pragma unroll
            for (int q = 0; q < 4; ++q) {
                int row = row0 + arow + rt * 16 + rq + q;
                if (row < n) h[(size_t)row * COUT + col] = f2bf(acc[rt][ct][q]);
            }
        }
    }
}

// ---------------- Gather (aggregation), bf16 source rows ----------------
template <int COLS, bool RELU>
__global__ __launch_bounds__(256) void k_gather(const ush* __restrict__ h,
                                                const int* __restrict__ rowstart,
                                                const int2* __restrict__ es,
                                                const float* __restrict__ inv,
                                                const float* __restrict__ bias,
                                                float* __restrict__ out, int n) {
    int wave = threadIdx.x >> 6;
    int lane = threadIdx.x & 63;
    int node = blockIdx.x * 4 + wave;
    if (node >= n) return;
    int s0 = rowstart[node];
    int s1 = rowstart[node + 1];
    float iv = inv[node];

    if constexpr (COLS == 128) {
        int c = lane * 2;
        float accx = 0.f, accy = 0.f;
        int i = s0;
        for (; i + 8 <= s1; i += 8) {
            int    a[8];
            float  w[8];
            uint32 u[8];
            #pragma unroll
            for (int j = 0; j < 8; ++j) {
                int2 r = es[i + j];
                a[j] = r.x;
                w[j] = __int_as_float(r.y);
            }
            #pragma unroll
            for (int j = 0; j < 8; ++j)
                u[j] = *(const uint32*)&h[(size_t)a[j] * 128 + c];
            #pragma unroll
            for (int j = 0; j < 8; ++j) {
                accx += w[j] * bfl(u[j]);
                accy += w[j] * bfh(u[j]);
            }
        }
        for (; i < s1; ++i) {
            int2 r = es[i];
            uint32 u = *(const uint32*)&h[(size_t)r.x * 128 + c];
            float w = __int_as_float(r.y);
            accx += w * bfl(u);
            accy += w * bfh(u);
        }
        uint32 us = *(const uint32*)&h[(size_t)node * 128 + c];
        float2 bb = *(const float2*)&bias[c];
        float ox = iv * accx + iv * iv * bfl(us) + bb.x;
        float oy = iv * accy + iv * iv * bfh(us) + bb.y;
        if (RELU) { ox = fmaxf(ox, 0.f); oy = fmaxf(oy, 0.f); }
        *(float2*)&out[node * 128 + c] = make_float2(ox, oy);
    } else {
        int c = lane;
        float acc = 0.f;
        int i = s0;
        for (; i + 8 <= s1; i += 8) {
            int   a[8];
            float w[8];
            ush   u[8];
            #pragma unroll
            for (int j = 0; j < 8; ++j) {
                int2 r = es[i + j];
                a[j] = r.x;
                w[j] = __int_as_float(r.y);
            }
            #pragma unroll
            for (int j = 0; j < 8; ++j)
                u[j] = h[(size_t)a[j] * 64 + c];
            #pragma unroll
            for (int j = 0; j < 8; ++j)
                acc += w[j] * bfl((uint32)u[j]);
        }
        for (; i < s1; ++i) {
            int2 r = es[i];
            acc += __int_as_float(r.y) * bfl((uint32)h[(size_t)r.x * 64 + c]);
        }
        float self = bfl((uint32)h[(size_t)node * 64 + c]);
        float o = iv * acc + iv * iv * self + bias[c];
        if (RELU) o = fmaxf(o, 0.f);
        out[node * 64 + c] = o;
    }
}

// ---------------- launcher ----------------

extern "C" void kernel_launch(void* const* d_in, const int* in_sizes, int n_in,
                              void* d_out, int out_size, void* d_ws, size_t ws_size,
                              hipStream_t stream) {
    const float* x  = (const float*)d_in[0];
    const int*   ei = (const int*)d_in[1];
    const float* W1 = (const float*)d_in[2];
    const float* b1 = (const float*)d_in[3];
    const float* W2 = (const float*)d_in[4];
    const float* b2 = (const float*)d_in[5];
    float* out = (float*)d_out;

    const int N = in_sizes[0] / 128;   // 50000
    const int E = in_sizes[1] / 2;     // 800000
    const int NB = (N + 63) >> BSH;    // 782 buckets
    const int* src = ei;
    const int* dstp = ei + E;

    char* p = (char*)d_ws;
    auto take = [&](size_t bytes) {
        char* r = p;
        p += (bytes + 255) & ~(size_t)255;
        return r;
    };
    float* inv      = (float*)take((size_t)N * 4);
    int*   rowstart = (int*)take((size_t)(N + 1) * 4);
    int*   bcnt     = (int*)take((size_t)NB * 4);
    int*   bstart   = (int*)take((size_t)(NB + 1) * 4);
    int*   bcur     = (int*)take((size_t)NB * 4);
    int2*  rec      = (int2*)take((size_t)E * 8);
    int2*  es       = (int2*)take((size_t)E * 8);
    ush*   w1h      = (ush*)take(16384 * 2);
    ush*   w1l      = (ush*)take(16384 * 2);
    ush*   w2h      = (ush*)take(8192 * 2);
    ush*   w2l      = (ush*)take(8192 * 2);
    ush*   h1       = (ush*)take((size_t)N * 128 * 2);   // bf16
    float* act1     = (float*)take((size_t)N * 128 * 4); // fp32
    ush*   h2       = h1;   // h1 dead after gather-1

    const int nbC = (E + CHUNK - 1) / CHUNK;

    // CSR build
    k_zerob <<<(NB + 255) / 256, 256, 0, stream>>>(bcnt, NB);
    k_bcount<<<nbC, 256, 0, stream>>>(dstp, bcnt, E, NB);
    k_bscan <<<1, 256, 0, stream>>>(bcnt, bstart, bcur, NB, E);
    k_binA2 <<<nbC, 256, 0, stream>>>(src, dstp, bcur, rec, E, NB);
    k_degB  <<<NB, 256, 0, stream>>>(rec, bstart, rowstart, inv, N, E);
    k_fillB2<<<NB, 256, 0, stream>>>(rec, bstart, rowstart, inv, es, N);

    // W pre-conversion (tiny)
    k_wcvt<<<64, 256, 0, stream>>>(W1, w1h, w1l, 7, 16384);
    k_wcvt<<<32, 256, 0, stream>>>(W2, w2h, w2l, 6, 8192);

    const int gb = (N + 127) / 128;   // 391
    k_gemm_mfma<128><<<gb, 256, 0, stream>>>(x, w1h, w1l, h1, N);
    k_gather<128, true><<<(N + 3) / 4, 256, 0, stream>>>(h1, rowstart, es, inv, b1, act1, N);
    k_gemm_mfma<64><<<gb, 256, 0, stream>>>(act1, w2h, w2l, h2, N);
    k_gather<64, false><<<(N + 3) / 4, 256, 0, stream>>>(h2, rowstart, es, inv, b2, out, N);
}